// Round 10
// baseline (544.518 us; speedup 1.0000x reference)
//
#include <hip/hip_runtime.h>
#include <hip/hip_bf16.h>
#include <float.h>

#define N_E   1024
#define CD    128
#define DELTA 0.45f

typedef __attribute__((ext_vector_type(4))) float f32x4;
typedef __attribute__((ext_vector_type(8))) short bf16x8;

static __device__ inline unsigned short f2bf(float f) {
    unsigned u = __float_as_uint(f);
    unsigned r = (u + 0x7fffu + ((u >> 16) & 1u)) >> 16;
    return (unsigned short)r;
}

// ---------------- Kernel 1: embed = emb @ proj_w^T + b ; ee ; ehi bf16
__global__ __launch_bounds__(128) void k_embed(const float* __restrict__ emb,
                                               const float* __restrict__ pw,
                                               const float* __restrict__ pb,
                                               float* __restrict__ embed,
                                               float* __restrict__ ee,
                                               unsigned short* __restrict__ ehi) {
    int j = blockIdx.x;
    int c = threadIdx.x;
    __shared__ float er[CD];
    __shared__ float red[CD];
    er[c] = emb[(size_t)j * CD + c];
    __syncthreads();
    float acc = pb[c];
    const float* pwr = pw + (size_t)c * CD;
    #pragma unroll 8
    for (int k = 0; k < CD; ++k) acc += er[k] * pwr[k];
    embed[(size_t)j * CD + c] = acc;
    ehi[(size_t)j * CD + c] = f2bf(acc);
    red[c] = acc * acc;
    __syncthreads();
    for (int off = 64; off > 0; off >>= 1) {
        if (c < off) red[c] += red[c + off];
        __syncthreads();
    }
    if (c == 0) ee[j] = red[0];
}

// ---------------- Kernel 2: QT=128, 8 waves M-split, NT=128 single-buf reg-staged pipeline
__global__ __launch_bounds__(512, 2) void k_vq(const float* __restrict__ x,
                                               const float* __restrict__ ee,
                                               const unsigned short* __restrict__ ehi,
                                               const float* __restrict__ embed,
                                               float* __restrict__ out_xq,
                                               float* __restrict__ out_idx,
                                               float* __restrict__ partials) {
    // region 32KB, two lives:
    //  phase A: Q-tile [128 q][16 chunks of 8 bf16], chunk ch of row m at ch^SW(m),
    //           SW(m)=(m&15)^(m>>4)
    //  phase B: one B tile ehi[128 codes][16 chunks]; LDS slot s of row n holds
    //           global chunk s^(n&15)  (reg-staged ds_write, swizzled on write)
    __shared__ alignas(64) unsigned short region[16384];
    __shared__ float qqpart[16][128];          // 8KB; later recheck qbuf (8x128 f)
    __shared__ float ee_s[N_E];
    __shared__ float qq[128];
    __shared__ int   bestjs[128];
    __shared__ unsigned flagm[8];

    const int t    = threadIdx.x;
    const int w    = t >> 6;                  // 8 waves; wave owns queries [16w,16w+16)
    const int lane = t & 63;
    const int lo4  = lane & 15;
    const int hi2  = lane >> 4;
    const int blk  = blockIdx.x;
    const int qbase = blk * 128;
    const int b    = blk >> 3;                // 8 blocks per image
    const int hw0  = (blk & 7) * 128;
    const float* xb = x + (size_t)b * 131072;

    if (t < 8) flagm[t] = 0;

    // ---- B tile 0: issue global loads into regs EARLY (lands during phase A)
    const int bn  = t >> 2;                    // LDS row this thread writes (0..127)
    const int bg0 = 4 * (t & 3);               // global chunk base within row
    f32x4 st[4];
    #pragma unroll
    for (int j = 0; j < 4; ++j)
        st[j] = *reinterpret_cast<const f32x4*>(&ehi[(size_t)bn * CD + (bg0 + j) * 8]);

    // ---- phase A: stage x-tile as bf16-hi (swizzled b128 writes) + qq partials
    const int f4 = t & 31;      // queries 4*f4 .. 4*f4+3
    const int cg = t >> 5;      // channel chunk cg: channels cg*8 .. cg*8+7
    {
        float4 v[8];
        #pragma unroll
        for (int r = 0; r < 8; ++r)
            v[r] = *reinterpret_cast<const float4*>(
                xb + (size_t)(cg * 8 + r) * 1024 + hw0 + 4 * f4);
        #pragma unroll
        for (int i = 0; i < 4; ++i) {
            const int m = 4 * f4 + i;
            const int sw = (m & 15) ^ (m >> 4);
            short hh[8];
            float q2 = 0.f;
            #pragma unroll
            for (int r = 0; r < 8; ++r) {
                const float f = (&v[r].x)[i];
                q2 = fmaf(f, f, q2);
                hh[r] = (short)f2bf(f);
            }
            *reinterpret_cast<bf16x8*>(&region[m * 128 + ((cg ^ sw) << 3)]) =
                bf16x8{hh[0], hh[1], hh[2], hh[3], hh[4], hh[5], hh[6], hh[7]};
            qqpart[cg][m] = q2;
        }
    }
    // ee_s loads (L2-resident, land whenever)
    for (int i = t; i < N_E; i += 512) ee_s[i] = ee[i];
    __syncthreads();
    if (t < 128) {
        float s = 0.f;
        #pragma unroll
        for (int c2 = 0; c2 < 16; ++c2) s += qqpart[c2][t];
        qq[t] = s;
    }
    __syncthreads();

    // ---- A-fragments into regs (wave's 16 queries), per-lane qq
    const int row_a = w * 16 + lo4;
    const int sw_a  = lo4 ^ w;                 // SW(row_a)
    bf16x8 a_hi[4];
    #pragma unroll
    for (int ks = 0; ks < 4; ++ks) {
        const int kc = ks * 4 + hi2;
        a_hi[ks] = *reinterpret_cast<const bf16x8*>(&region[row_a * 128 + ((kc ^ sw_a) << 3)]);
    }
    float qq_s[4];
    #pragma unroll
    for (int r = 0; r < 4; ++r) qq_s[r] = qq[w * 16 + hi2 * 4 + r];
    __syncthreads();                           // Q-region reads complete

    // ---- write B tile 0 (swizzled slots), then it's live
    const int bslot0 = bn * 128;               // shorts
    const int nmask  = bn & 15;
    #pragma unroll
    for (int j = 0; j < 4; ++j)
        *reinterpret_cast<f32x4*>(&region[bslot0 + (((bg0 + j) ^ nmask) << 3)]) = st[j];
    __syncthreads();

    float b1[4], b2[4], sacc[4];
    int   j1[4];
    #pragma unroll
    for (int s = 0; s < 4; ++s) { b1[s] = FLT_MAX; b2[s] = FLT_MAX; sacc[s] = 0.f; j1[s] = 0; }

    #pragma unroll 1
    for (int tile = 0; tile < 8; ++tile) {
        // issue next tile's global loads (latency hidden under this tile's compute)
        if (tile < 7) {
            #pragma unroll
            for (int j = 0; j < 4; ++j)
                st[j] = *reinterpret_cast<const f32x4*>(
                    &ehi[(size_t)((tile + 1) * 128 + bn) * CD + (bg0 + j) * 8]);
        }

        const int jb = tile * 128;
        #pragma unroll
        for (int nt = 0; nt < 8; ++nt) {
            const int n = nt * 16 + lo4;
            f32x4 acc = {0.f, 0.f, 0.f, 0.f};
            #pragma unroll
            for (int ks = 0; ks < 4; ++ks) {
                const int kc = ks * 4 + hi2;
                const bf16x8 bfr = *reinterpret_cast<const bf16x8*>(
                    &region[n * 128 + ((kc ^ lo4) << 3)]);
                acc = __builtin_amdgcn_mfma_f32_16x16x32_bf16(a_hi[ks], bfr, acc, 0, 0, 0);
            }
            const int nj = jb + n;
            const float ee_r = ee_s[nj];
            #pragma unroll
            for (int r = 0; r < 4; ++r) {
                float d2 = fmaf(-2.f, acc[r], qq_s[r] + ee_r);
                d2 = fmaxf(d2, 0.f);
                b2[r] = fminf(b2[r], fmaxf(b1[r], d2));
                const bool lt = d2 < b1[r];
                j1[r] = lt ? nj : j1[r];
                b1[r] = lt ? d2 : b1[r];
                sacc[r] += __expf(16.f - sqrtf(d2));
            }
        }

        __syncthreads();                       // all waves done reading this tile
        if (tile < 7) {
            #pragma unroll
            for (int j = 0; j < 4; ++j)
                *reinterpret_cast<f32x4*>(&region[bslot0 + (((bg0 + j) ^ nmask) << 3)]) = st[j];
            __syncthreads();                   // next tile ready
        }
    }

    // ---- per-wave merge across lo4 (codes), flags, loss partial — wave owns its queries
    unsigned flagbits = 0;
    float lsum = 0.f;
    #pragma unroll
    for (int r = 0; r < 4; ++r) {
        float B1 = b1[r]; int J1 = j1[r]; float B2 = b2[r]; float S = sacc[r];
        #pragma unroll
        for (int d = 1; d <= 8; d <<= 1) {
            const float o1 = __shfl_xor(B1, d);
            const int   oj = __shfl_xor(J1, d);
            const float o2 = __shfl_xor(B2, d);
            const float os = __shfl_xor(S, d);
            const float mx = fmaxf(B1, o1);
            B2 = fminf(fminf(B2, o2), mx);
            const bool take = (o1 < B1) || (o1 == B1 && oj < J1);
            B1 = take ? o1 : B1;
            J1 = take ? oj : J1;
            S += os;
        }
        if (lo4 == 0) {
            const int mloc = hi2 * 4 + r;
            bestjs[w * 16 + mloc] = J1;
            out_idx[qbase + w * 16 + mloc] = (float)J1;
            if (B2 - B1 < DELTA) flagbits |= (1u << mloc);
            lsum += sqrtf(fmaxf(B1, 0.f)) - 16.f + __logf(S);
        }
    }
    if (lo4 == 0) atomicOr(&flagm[w], flagbits);
    lsum += __shfl_down(lsum, 16);
    lsum += __shfl_down(lsum, 32);
    if (lane == 0) partials[blk * 8 + w] = lsum;
    __syncthreads();

    // ---- exact fp32 recheck for near-tie queries (per wave, own rows)
    float* qbufw = &qqpart[0][0] + w * 128;
    unsigned fm = flagm[w];
    while (fm) {
        const int mloc = __builtin_ctz(fm);
        fm &= fm - 1;
        const int m = w * 16 + mloc;
        const int hw = hw0 + m;
        qbufw[lane]      = xb[(size_t)lane * 1024 + hw];
        qbufw[64 + lane] = xb[(size_t)(lane + 64) * 1024 + hw];
        __threadfence_block();
        const float qqm = qq[m];
        float dbest = FLT_MAX; int jbest = 0;
        for (int tt = 0; tt < 16; ++tt) {
            const int j = tt * 64 + lane;
            float dot = 0.f;
            #pragma unroll 8
            for (int c4 = 0; c4 < 32; ++c4) {
                const f32x4 evv = *reinterpret_cast<const f32x4*>(&embed[j * CD + 4 * c4]);
                const f32x4 qv  = *reinterpret_cast<const f32x4*>(&qbufw[4 * c4]);
                dot = fmaf(evv[0], qv[0], dot);
                dot = fmaf(evv[1], qv[1], dot);
                dot = fmaf(evv[2], qv[2], dot);
                dot = fmaf(evv[3], qv[3], dot);
            }
            float d2 = fmaf(-2.f, dot, qqm + ee_s[j]);
            d2 = fmaxf(d2, 0.f);
            if (d2 < dbest || (d2 == dbest && j < jbest)) { dbest = d2; jbest = j; }
        }
        #pragma unroll
        for (int d = 1; d <= 32; d <<= 1) {
            const float od = __shfl_xor(dbest, d);
            const int   oj = __shfl_xor(jbest, d);
            if (od < dbest || (od == dbest && oj < jbest)) { dbest = od; jbest = oj; }
        }
        if (lane == 0) {
            bestjs[m] = jbest;
            out_idx[qbase + m] = (float)jbest;
        }
    }
    __syncthreads();

    // ---- gather x_q
    const int jq0 = bestjs[4 * f4 + 0];
    const int jq1 = bestjs[4 * f4 + 1];
    const int jq2 = bestjs[4 * f4 + 2];
    const int jq3 = bestjs[4 * f4 + 3];
    float* ob = out_xq + (size_t)b * 131072 + hw0 + 4 * f4;
    #pragma unroll
    for (int r = 0; r < 8; ++r) {
        const int c = cg * 8 + r;
        float4 v;
        v.x = embed[jq0 * CD + c];
        v.y = embed[jq1 * CD + c];
        v.z = embed[jq2 * CD + c];
        v.w = embed[jq3 * CD + c];
        *reinterpret_cast<float4*>(ob + (size_t)c * 1024) = v;
    }
}

// ---------------- Kernel 3: deterministic loss reduction
__global__ __launch_bounds__(256) void k_loss(const float* __restrict__ partials,
                                              float* __restrict__ out_loss) {
    __shared__ float red[256];
    const int t = threadIdx.x;
    float v = 0.f;
    for (int i = t; i < 4096; i += 256) v += partials[i];
    red[t] = v;
    __syncthreads();
    for (int off = 128; off; off >>= 1) {
        if (t < off) red[t] += red[t + off];
        __syncthreads();
    }
    if (t == 0) out_loss[0] = red[0] * (1.0f / 65536.0f);
}

extern "C" void kernel_launch(void* const* d_in, const int* in_sizes, int n_in,
                              void* d_out, int out_size, void* d_ws, size_t ws_size,
                              hipStream_t stream) {
    const float* x   = (const float*)d_in[0];   // (64,128,32,32)
    const float* emb = (const float*)d_in[1];   // (1024,128)
    const float* pw  = (const float*)d_in[2];   // (128,128)
    const float* pb  = (const float*)d_in[3];   // (128,)

    float* out = (float*)d_out;
    float* out_xq   = out;                 // 8388608 floats
    float* out_loss = out + 8388608;       // 1 float
    float* out_idx  = out + 8388609;       // 65536 floats

    float* embed    = (float*)d_ws;                       // 1024*128 fp32
    float* ee       = embed + N_E * CD;                   // 1024
    float* partials = ee + N_E;                           // 4096
    unsigned short* ehi = (unsigned short*)(partials + 4096);   // 1024*128 bf16

    k_embed<<<N_E, 128, 0, stream>>>(emb, pw, pb, embed, ee, ehi);
    k_vq<<<512, 512, 0, stream>>>(x, ee, ehi, embed, out_xq, out_idx, partials);
    k_loss<<<1, 256, 0, stream>>>(partials, out_loss);
}

// Round 11
// 375.153 us; speedup vs baseline: 1.4515x; 1.4515x over previous
//
#include <hip/hip_runtime.h>
#include <hip/hip_bf16.h>
#include <float.h>

#define N_E   1024
#define CD    128
#define DELTA 0.32f

typedef __attribute__((ext_vector_type(4))) float f32x4;
typedef __attribute__((ext_vector_type(8))) short bf16x8;

static __device__ inline unsigned short f2bf(float f) {
    unsigned u = __float_as_uint(f);
    unsigned r = (u + 0x7fffu + ((u >> 16) & 1u)) >> 16;
    return (unsigned short)r;
}
static __device__ inline float bf2f(unsigned short s) {
    return __uint_as_float(((unsigned)s) << 16);
}

// ---------------- Kernel 1: embed = emb @ proj_w^T + b ; ee ; ehi bf16
__global__ __launch_bounds__(128) void k_embed(const float* __restrict__ emb,
                                               const float* __restrict__ pw,
                                               const float* __restrict__ pb,
                                               float* __restrict__ embed,
                                               float* __restrict__ ee,
                                               unsigned short* __restrict__ ehi) {
    int j = blockIdx.x;
    int c = threadIdx.x;
    __shared__ float er[CD];
    __shared__ float red[CD];
    er[c] = emb[(size_t)j * CD + c];
    __syncthreads();
    float acc = pb[c];
    const float* pwr = pw + (size_t)c * CD;
    #pragma unroll 8
    for (int k = 0; k < CD; ++k) acc += er[k] * pwr[k];
    embed[(size_t)j * CD + c] = acc;
    ehi[(size_t)j * CD + c] = f2bf(acc);
    red[c] = acc * acc;
    __syncthreads();
    for (int off = 64; off > 0; off >>= 1) {
        if (c < off) red[c] += red[c + off];
        __syncthreads();
    }
    if (c == 0) ee[j] = red[0];
}

// ---------------- Kernel 2: round-6 structure, ehi-only B (2-pass qhi/qlo vs ehi)
__global__ __launch_bounds__(512, 4) void k_vq(const float* __restrict__ x,
                                               const float* __restrict__ ee,
                                               const unsigned short* __restrict__ ehi,
                                               const float* __restrict__ embed,
                                               float* __restrict__ out_xq,
                                               float* __restrict__ out_idx,
                                               float* __restrict__ partials) {
    // Phase 1: smem = x-tile [128 rows][32 chunks of 8 shorts], chunk cc stored at cc^SW(m),
    //          SW(m) = (m&15)^(m>>4); chunks 0-15 = qhi, 16-31 = qlo.
    // Phase 2: smem = B dbuf, each buf 8192 shorts = ehi[64][128];
    //          LDS slot s of row n holds global chunk s^(n&15) (linear dest, swizzled src).
    __shared__ alignas(64) unsigned short smem[2 * 16384];
    __shared__ float qq[128];
    __shared__ float qqpart[8][128];
    __shared__ float ee_s[N_E];
    __shared__ int   bestjs[128];
    __shared__ unsigned flagm[8];
    __shared__ alignas(16) float qbuf[8][128];

    const int t    = threadIdx.x;
    const int w    = t >> 6;          // 8 waves
    const int lane = t & 63;
    const int lo4  = lane & 15;
    const int hi2  = lane >> 4;
    const int blk  = blockIdx.x;
    const int qbase = blk * 128;
    const int b    = blk >> 3;
    const int hw0  = (blk & 7) * 128;
    const float* xb = x + (size_t)b * 131072;

    if (t < 8) flagm[t] = 0;
    for (int i = t; i < N_E; i += 512) ee_s[i] = ee[i];

    // ---- phase A: stage x-tile as hi/lo bf16 (swizzled b128 writes) + qq partials
    const int f4 = t & 31;            // queries 4*f4 .. 4*f4+3
    const int cg = t >> 5;            // channel chunk cg: channels cg*8 .. cg*8+7
    float4 xv[8];
    #pragma unroll
    for (int r = 0; r < 8; ++r)
        xv[r] = *reinterpret_cast<const float4*>(xb + (size_t)(cg * 8 + r) * 1024 + hw0 + 4 * f4);
    float qql[4] = {0.f, 0.f, 0.f, 0.f};
    #pragma unroll
    for (int i = 0; i < 4; ++i) {
        const int m = 4 * f4 + i;
        const int sw = (m & 15) ^ (m >> 4);
        short hh[8], ll[8];
        #pragma unroll
        for (int r = 0; r < 8; ++r) {
            const float f = (&xv[r].x)[i];
            qql[i] = fmaf(f, f, qql[i]);
            const unsigned short h = f2bf(f);
            hh[r] = (short)h;
            ll[r] = (short)f2bf(f - bf2f(h));
        }
        const int ch = cg ^ sw;
        *reinterpret_cast<bf16x8*>(&smem[m * 256 + (ch << 3)]) =
            bf16x8{hh[0], hh[1], hh[2], hh[3], hh[4], hh[5], hh[6], hh[7]};
        *reinterpret_cast<bf16x8*>(&smem[m * 256 + 128 + (ch << 3)]) =
            bf16x8{ll[0], ll[1], ll[2], ll[3], ll[4], ll[5], ll[6], ll[7]};
    }
    #pragma unroll
    for (int i = 0; i < 4; ++i) qql[i] += __shfl_xor(qql[i], 32);
    if (lane < 32) {
        #pragma unroll
        for (int i = 0; i < 4; ++i) qqpart[w][4 * lane + i] = qql[i];
    }
    __syncthreads();
    if (t < 128) {
        float s = 0.f;
        #pragma unroll
        for (int ww = 0; ww < 8; ++ww) s += qqpart[ww][t];
        qq[t] = s;
    }
    __syncthreads();

    // ---- A-fragments (qhi, qlo) into registers; wave owns queries mb..mb+15
    const int mb = w * 16;
    const int m_a = mb + lo4;
    const int sw_a = lo4 ^ w;         // SW(m) for m = w*16+lo4
    bf16x8 a_hi[4], a_lo[4];
    #pragma unroll
    for (int ks = 0; ks < 4; ++ks) {
        const int kc = ks * 4 + hi2;
        a_hi[ks] = *reinterpret_cast<const bf16x8*>(&smem[m_a * 256 + ((kc ^ sw_a) << 3)]);
        a_lo[ks] = *reinterpret_cast<const bf16x8*>(&smem[m_a * 256 + 128 + ((kc ^ sw_a) << 3)]);
    }
    float qq_s[4];
    #pragma unroll
    for (int r = 0; r < 4; ++r) qq_s[r] = qq[mb + hi2 * 4 + r];
    __syncthreads();   // all waves done reading x-region; safe to overwrite with B tiles

    // ---- B staging: 2 global_load_lds (16B) per wave per tile (ehi only)
    auto stage = [&](int jb, int bufsel) {
        #pragma unroll
        for (int j = 0; j < 2; ++j) {
            const int cidx = w * 128 + j * 64 + lane;    // 16B chunk in [0,1024)
            const int n = cidx >> 4, s = cidx & 15;
            const int g = s ^ (n & 15);
            const unsigned short* src = ehi + (size_t)(jb + n) * CD + g * 8;
            unsigned short* dst = &smem[bufsel * 8192 + cidx * 8];  // wave-uniform base
            __builtin_amdgcn_global_load_lds(
                (const __attribute__((address_space(1))) void*)src,
                (__attribute__((address_space(3))) void*)dst, 16, 0, 0);
        }
    };

    stage(0, 0);
    __syncthreads();   // buf0 ready (syncthreads drains vmcnt)

    float b1[4], b2[4], sacc[4];
    int   j1[4];
    #pragma unroll
    for (int s = 0; s < 4; ++s) { b1[s] = FLT_MAX; b2[s] = FLT_MAX; sacc[s] = 0.f; j1[s] = 0; }

    #pragma unroll 1
    for (int tile = 0; tile < 16; ++tile) {
        if (tile < 15) stage((tile + 1) * 64, (tile + 1) & 1);   // prefetch next buf

        const unsigned short* bb = &smem[(tile & 1) * 8192];
        const int jb = tile * 64;
        float ee_r[4];
        #pragma unroll
        for (int tn = 0; tn < 4; ++tn) ee_r[tn] = ee_s[jb + tn * 16 + lo4];

        f32x4 acc[4];
        const f32x4 zero = {0.f, 0.f, 0.f, 0.f};
        #pragma unroll
        for (int tn = 0; tn < 4; ++tn) acc[tn] = zero;

        #pragma unroll
        for (int ks = 0; ks < 4; ++ks) {
            const int kc = ks * 4 + hi2;
            bf16x8 bfr[4];
            #pragma unroll
            for (int tn = 0; tn < 4; ++tn) {
                const int n = tn * 16 + lo4;
                bfr[tn] = *reinterpret_cast<const bf16x8*>(
                    &bb[n * CD + ((kc ^ (n & 15)) << 3)]);
            }
            #pragma unroll
            for (int tn = 0; tn < 4; ++tn) {
                acc[tn] = __builtin_amdgcn_mfma_f32_16x16x32_bf16(a_hi[ks], bfr[tn], acc[tn], 0, 0, 0);
                acc[tn] = __builtin_amdgcn_mfma_f32_16x16x32_bf16(a_lo[ks], bfr[tn], acc[tn], 0, 0, 0);
            }
        }

        // ---- fold: d2 ; top-2 ; fixed-frame LSE
        #pragma unroll
        for (int tn = 0; tn < 4; ++tn) {
            const int n = jb + tn * 16 + lo4;
            #pragma unroll
            for (int r = 0; r < 4; ++r) {
                float d2 = fmaf(-2.f, acc[tn][r], qq_s[r] + ee_r[tn]);
                d2 = fmaxf(d2, 0.f);
                b2[r] = fminf(b2[r], fmaxf(b1[r], d2));
                const bool lt = d2 < b1[r];
                j1[r] = lt ? n : j1[r];
                b1[r] = lt ? d2 : b1[r];
                sacc[r] += __expf(16.f - sqrtf(d2));
            }
        }

        __syncthreads();   // drains prefetch vmcnt; all waves done reading bb
    }

    // ---- per-wave merge across lo4 (codes), flags, loss partial
    unsigned flagbits = 0;
    float lsum = 0.f;
    #pragma unroll
    for (int r = 0; r < 4; ++r) {
        float B1 = b1[r]; int J1 = j1[r]; float B2 = b2[r]; float S = sacc[r];
        #pragma unroll
        for (int d = 1; d <= 8; d <<= 1) {
            const float o1 = __shfl_xor(B1, d);
            const int   oj = __shfl_xor(J1, d);
            const float o2 = __shfl_xor(B2, d);
            const float os = __shfl_xor(S, d);
            const float mx = fmaxf(B1, o1);
            B2 = fminf(fminf(B2, o2), mx);
            const bool take = (o1 < B1) || (o1 == B1 && oj < J1);
            B1 = take ? o1 : B1;
            J1 = take ? oj : J1;
            S += os;
        }
        if (lo4 == 0) {
            const int mloc = hi2 * 4 + r;
            bestjs[mb + mloc] = J1;
            out_idx[qbase + mb + mloc] = (float)J1;
            if (B2 - B1 < DELTA) flagbits |= (1u << mloc);
            lsum += sqrtf(fmaxf(B1, 0.f)) - 16.f + __logf(S);
        }
    }
    if (lo4 == 0) atomicOr(&flagm[w], flagbits);
    lsum += __shfl_down(lsum, 16);
    lsum += __shfl_down(lsum, 32);
    if (lane == 0) partials[blk * 8 + w] = lsum;
    __syncthreads();

    // ---- exact fp32 recheck for near-tie queries (per wave, own rows)
    unsigned fm = flagm[w];
    while (fm) {
        const int mloc = __builtin_ctz(fm);
        fm &= fm - 1;
        const int m = mb + mloc;
        const int hw = hw0 + m;
        qbuf[w][lane]      = xb[(size_t)lane * 1024 + hw];
        qbuf[w][64 + lane] = xb[(size_t)(lane + 64) * 1024 + hw];
        __threadfence_block();
        const float qqm = qq[m];
        float dbest = FLT_MAX; int jbest = 0;
        for (int tt = 0; tt < 16; ++tt) {
            const int j = tt * 64 + lane;
            float dot = 0.f;
            #pragma unroll 8
            for (int c4 = 0; c4 < 32; ++c4) {
                const f32x4 evv = *reinterpret_cast<const f32x4*>(&embed[j * CD + 4 * c4]);
                const f32x4 qv  = *reinterpret_cast<const f32x4*>(&qbuf[w][4 * c4]);
                dot = fmaf(evv[0], qv[0], dot);
                dot = fmaf(evv[1], qv[1], dot);
                dot = fmaf(evv[2], qv[2], dot);
                dot = fmaf(evv[3], qv[3], dot);
            }
            float d2 = fmaf(-2.f, dot, qqm + ee_s[j]);
            d2 = fmaxf(d2, 0.f);
            if (d2 < dbest || (d2 == dbest && j < jbest)) { dbest = d2; jbest = j; }
        }
        #pragma unroll
        for (int d = 1; d <= 32; d <<= 1) {
            const float od = __shfl_xor(dbest, d);
            const int   oj = __shfl_xor(jbest, d);
            if (od < dbest || (od == dbest && oj < jbest)) { dbest = od; jbest = oj; }
        }
        if (lane == 0) {
            bestjs[m] = jbest;
            out_idx[qbase + m] = (float)jbest;
        }
    }
    __syncthreads();

    // ---- gather x_q
    const int jq0 = bestjs[4 * f4 + 0];
    const int jq1 = bestjs[4 * f4 + 1];
    const int jq2 = bestjs[4 * f4 + 2];
    const int jq3 = bestjs[4 * f4 + 3];
    float* ob = out_xq + (size_t)b * 131072 + hw0 + 4 * f4;
    #pragma unroll
    for (int r = 0; r < 8; ++r) {
        const int c = cg * 8 + r;
        float4 v;
        v.x = embed[jq0 * CD + c];
        v.y = embed[jq1 * CD + c];
        v.z = embed[jq2 * CD + c];
        v.w = embed[jq3 * CD + c];
        *reinterpret_cast<float4*>(ob + (size_t)c * 1024) = v;
    }
}

// ---------------- Kernel 3: deterministic loss reduction
__global__ __launch_bounds__(256) void k_loss(const float* __restrict__ partials,
                                              float* __restrict__ out_loss) {
    __shared__ float red[256];
    const int t = threadIdx.x;
    float v = 0.f;
    for (int i = t; i < 4096; i += 256) v += partials[i];
    red[t] = v;
    __syncthreads();
    for (int off = 128; off; off >>= 1) {
        if (t < off) red[t] += red[t + off];
        __syncthreads();
    }
    if (t == 0) out_loss[0] = red[0] * (1.0f / 65536.0f);
}

extern "C" void kernel_launch(void* const* d_in, const int* in_sizes, int n_in,
                              void* d_out, int out_size, void* d_ws, size_t ws_size,
                              hipStream_t stream) {
    const float* x   = (const float*)d_in[0];   // (64,128,32,32)
    const float* emb = (const float*)d_in[1];   // (1024,128)
    const float* pw  = (const float*)d_in[2];   // (128,128)
    const float* pb  = (const float*)d_in[3];   // (128,)

    float* out = (float*)d_out;
    float* out_xq   = out;                 // 8388608 floats
    float* out_loss = out + 8388608;       // 1 float
    float* out_idx  = out + 8388609;       // 65536 floats

    float* embed    = (float*)d_ws;                       // 1024*128 fp32
    float* ee       = embed + N_E * CD;                   // 1024
    float* partials = ee + N_E;                           // 4096
    unsigned short* ehi = (unsigned short*)(partials + 4096);   // 1024*128 bf16

    k_embed<<<N_E, 128, 0, stream>>>(emb, pw, pb, embed, ee, ehi);
    k_vq<<<512, 512, 0, stream>>>(x, ee, ehi, embed, out_xq, out_idx, partials);
    k_loss<<<1, 256, 0, stream>>>(partials, out_loss);
}